// Round 1
// baseline (1071.482 us; speedup 1.0000x reference)
//
#include <hip/hip_runtime.h>
#include <cstdint>
#include <cstddef>

#define NB 256
#define NS 2500
#define NJ 24
#define DF 131

#define K1G 8            // c-split groups in k1
#define TN 124           // n-rows per LDS tile in k2/k4 (124*131*4 = 64976 B < 64 KiB)
#define NHALF 1250       // n-rows handled per block (2 blocks per batch)
#define NTILE 11         // ceil(1250/124)

// ws layout (float offsets)
#define WS_W1T 0u
#define WS_QT  60000u                                  // [NB][DF][NJ]
#define WS_MD  (WS_QT + (unsigned)(NB * DF * NJ))      // [NB][2][48] (m,d per half)
#define WS_PO  (WS_MD + (unsigned)(NB * 2 * 48))       // [2][NB][NJ][DF]

// ---------------- W1 transpose: W1t[c][o] = W1[o][c] ----------------
__global__ __launch_bounds__(256) void kT(const float* __restrict__ W1,
                                          float* __restrict__ W1t) {
  int i = blockIdx.x * 256 + threadIdx.x;
  if (i >= NJ * NS) return;
  int o = i / NS, c = i - o * NS;
  W1t[c * NJ + o] = W1[i];
}

// ---------------- h partials: part[(b*8+g)][o][l] = sum_{c in group g} W1t[c][o]*X[b][c][l]
__global__ __launch_bounds__(512) void k1(const float* __restrict__ sf,
                                          const float* __restrict__ W1t,
                                          float* __restrict__ part) {
  int flat = blockIdx.x * 512 + threadIdx.x;   // exactly NB*K1G*DF = 268288 threads
  int l = flat % DF;
  int bg = flat / DF;                          // b*8+g
  int g = bg & (K1G - 1);
  int b = bg >> 3;
  int c0 = g * 313 - (g > 4 ? (g - 4) : 0);    // 0,313,626,939,1252,1564,1876,2188
  int cnt = (g < 4) ? 313 : 312;

  const float* sp = sf + (size_t)b * (NS * DF) + (size_t)c0 * DF + l;
  const float* wp = W1t + c0 * NJ;

  float acc[NJ];
#pragma unroll
  for (int o = 0; o < NJ; ++o) acc[o] = 0.f;

#pragma unroll 2
  for (int cc = 0; cc < cnt; ++cc) {
    float xv = sp[(size_t)cc * DF];            // coalesced vector load
#pragma unroll
    for (int o = 0; o < NJ; ++o)               // W1t uniform -> s_load broadcast
      acc[o] = fmaf(wp[cc * NJ + o], xv, acc[o]);
  }
  float* pp = part + (size_t)bg * (NJ * DF) + l;
#pragma unroll
  for (int o = 0; o < NJ; ++o) pp[o * DF] = acc[o];
}

// ---------------- reduce partials, relu, query = W2@h + b2, store q^T [b][l][24]
__global__ __launch_bounds__(512) void k1b(const float* __restrict__ part,
                                           const float* __restrict__ W2,
                                           const float* __restrict__ b1v,
                                           const float* __restrict__ b2v,
                                           float* __restrict__ q_t) {
  int flat = blockIdx.x * 512 + threadIdx.x;
  if (flat >= NB * DF) return;
  int l = flat % DF;
  int b = flat / DF;

  float h[NJ];
#pragma unroll
  for (int o = 0; o < NJ; ++o) h[o] = b1v[o];
  for (int g = 0; g < K1G; ++g) {
    const float* pp = part + (size_t)(b * K1G + g) * (NJ * DF) + l;
#pragma unroll
    for (int o = 0; o < NJ; ++o) h[o] += pp[o * DF];
  }
#pragma unroll
  for (int o = 0; o < NJ; ++o) h[o] = fmaxf(h[o], 0.f);

  float q[NJ];
  for (int o = 0; o < NJ; ++o) {
    float s = b2v[o];
#pragma unroll
    for (int i = 0; i < NJ; ++i) s = fmaf(W2[o * NJ + i], h[i], s);
    q[o] = s;
  }
  float4* qp = (float4*)(q_t + (size_t)flat * NJ);   // 96B-aligned
#pragma unroll
  for (int v = 0; v < 6; ++v)
    qp[v] = make_float4(q[4 * v], q[4 * v + 1], q[4 * v + 2], q[4 * v + 3]);
}

// ---------------- scores + online m/d. block = (batch, n-half). writes raw S.
__global__ __launch_bounds__(512) void k2(const float* __restrict__ sf,
                                          const float* __restrict__ q_t,
                                          float* __restrict__ raw,
                                          float* __restrict__ md) {
  __shared__ float xs[TN * DF];                // flat [n][l], stride 131 (bank-clean)
  __shared__ float lmd[8][6][2];
  int b = blockIdx.x >> 1;
  int h = blockIdx.x & 1;
  int tid = threadIdx.x;
  int wid = tid >> 6, lane = tid & 63;
  int jq = __builtin_amdgcn_readfirstlane(wid >> 1);  // 0..3 -> 6 j's each
  int ng = wid & 1;
  int nl = ng * 64 + lane;                      // 0..127 (valid < TN)

  const float* sft = sf + (size_t)b * (NS * DF) + (size_t)h * (NHALF * DF);
  const float* qb = q_t + (size_t)b * (DF * NJ) + jq * 6;
  float* rawb = raw + (size_t)b * (NJ * NS) + (size_t)h * NHALF;

  float m_loc[6], d_loc[6];
#pragma unroll
  for (int i = 0; i < 6; ++i) { m_loc[i] = -1e30f; d_loc[i] = 0.f; }

  const int EC = TN * DF;                       // 16244
  float st[32];
#pragma unroll
  for (int k = 0; k < 32; ++k) {                // preload tile 0 (flat copy)
    int e = tid + k * 512;
    st[k] = (e < EC) ? sft[e] : 0.f;
  }

  int nle = (nl < TN) ? nl : 0;                 // keep LDS reads in-bounds
  for (int t = 0; t < NTILE; ++t) {
    __syncthreads();
#pragma unroll
    for (int k = 0; k < 32; ++k) {
      int e = tid + k * 512;
      if (e < EC) xs[e] = st[k];
    }
    __syncthreads();
    if (t + 1 < NTILE) {                        // issue next tile's loads now
      size_t base = (size_t)(t + 1) * EC;
#pragma unroll
      for (int k = 0; k < 32; ++k) {
        int e = tid + k * 512;
        bool ok = (e < EC) && ((t + 1) * EC + e < NHALF * DF);
        st[k] = ok ? sft[base + e] : 0.f;
      }
    }
    float s_acc[6];
#pragma unroll
    for (int i = 0; i < 6; ++i) s_acc[i] = 0.f;
    const float* xrow = xs + nle * DF;
    for (int l = 0; l < DF; ++l) {
      float xv = xrow[l];                       // ds_read, (3n+l)%32 conflict-free
#pragma unroll
      for (int i = 0; i < 6; ++i)               // q uniform -> s_load
        s_acc[i] = fmaf(qb[l * NJ + i], xv, s_acc[i]);
    }
    int nrow = t * TN + nl;
    if (nl < TN && nrow < NHALF) {
#pragma unroll
      for (int i = 0; i < 6; ++i) {
        rawb[(size_t)(jq * 6 + i) * NS + nrow] = s_acc[i];
        float mn = fmaxf(m_loc[i], s_acc[i]);
        d_loc[i] = d_loc[i] * __expf(m_loc[i] - mn) + __expf(s_acc[i] - mn);
        m_loc[i] = mn;
      }
    }
  }
  // lane butterfly reduce (m,d) then cross-wave combine
#pragma unroll
  for (int i = 0; i < 6; ++i) {
    float m = m_loc[i], d = d_loc[i];
    for (int off = 32; off > 0; off >>= 1) {
      float mo = __shfl_xor(m, off);
      float dd = __shfl_xor(d, off);
      float nm = fmaxf(m, mo);
      d = d * __expf(m - nm) + dd * __expf(mo - nm);
      m = nm;
    }
    if (lane == 0) { lmd[wid][i][0] = m; lmd[wid][i][1] = d; }
  }
  __syncthreads();
  if (tid < NJ) {
    int j = tid, j6 = j / 6, i = j % 6;
    float m1 = lmd[j6 * 2][i][0],     d1 = lmd[j6 * 2][i][1];
    float m2 = lmd[j6 * 2 + 1][i][0], d2 = lmd[j6 * 2 + 1][i][1];
    float nm = fmaxf(m1, m2);
    float dd = d1 * __expf(m1 - nm) + d2 * __expf(m2 - nm);
    md[(size_t)(b * 2 + h) * 48 + j] = nm;
    md[(size_t)(b * 2 + h) * 48 + 24 + j] = dd;
  }
}

// ---------------- combine half m/d, normalize attention in place
__global__ __launch_bounds__(256) void k3(float* __restrict__ attn,
                                          const float* __restrict__ md) {
  int bj = blockIdx.x;                          // b*24+j
  int b = bj / NJ;
  int j = bj - b * NJ;
  const float* mp = md + (size_t)b * 96;
  float m1 = mp[j], d1 = mp[24 + j], m2 = mp[48 + j], d2 = mp[72 + j];
  float m = fmaxf(m1, m2);
  float r = 1.f / (d1 * __expf(m1 - m) + d2 * __expf(m2 - m));
  float* p = attn + (size_t)bj * NS;
  for (int n = threadIdx.x; n < NS; n += 256)
    p[n] = __expf(p[n] - m) * r;
}

// ---------------- out partials: po[h][b][j][l] = sum_{n in half} A[b][j][n]*X[b][n][l]
__global__ __launch_bounds__(768) void k4(const float* __restrict__ sf,
                                          const float* __restrict__ attn,
                                          float* __restrict__ pout) {
  __shared__ float xs[TN * DF];
  int b = blockIdx.x >> 1;
  int h = blockIdx.x & 1;
  int tid = threadIdx.x;
  int wid = tid >> 6, lane = tid & 63;
  int jq = __builtin_amdgcn_readfirstlane(wid & 3);   // 0..3
  int lg = wid >> 2;                                  // 0..2
  int l = lg * 64 + lane;                             // 0..191, active < DF

  const float* sft = sf + (size_t)b * (NS * DF) + (size_t)h * (NHALF * DF);
  const float* ab = attn + (size_t)(b * NJ + jq * 6) * NS + (size_t)h * NHALF;

  float acc[6];
#pragma unroll
  for (int i = 0; i < 6; ++i) acc[i] = 0.f;

  const int EC = TN * DF;
  float st[22];
#pragma unroll
  for (int k = 0; k < 22; ++k) {
    int e = tid + k * 768;
    st[k] = (e < EC) ? sft[e] : 0.f;
  }
  int lc = (l < DF) ? l : 0;
  for (int t = 0; t < NTILE; ++t) {
    __syncthreads();
#pragma unroll
    for (int k = 0; k < 22; ++k) {
      int e = tid + k * 768;
      if (e < EC) xs[e] = st[k];
    }
    __syncthreads();
    if (t + 1 < NTILE) {
      size_t base = (size_t)(t + 1) * EC;
#pragma unroll
      for (int k = 0; k < 22; ++k) {
        int e = tid + k * 768;
        bool ok = (e < EC) && ((t + 1) * EC + e < NHALF * DF);
        st[k] = ok ? sft[base + e] : 0.f;
      }
    }
    int nmax = NHALF - t * TN; if (nmax > TN) nmax = TN;
#pragma unroll 4
    for (int n = 0; n < nmax; ++n) {
      float xv = xs[n * DF + lc];               // lanes->l consecutive, bank-clean
#pragma unroll
      for (int i = 0; i < 6; ++i)               // attn uniform -> s_load
        acc[i] = fmaf(ab[(size_t)i * NS + t * TN + n], xv, acc[i]);
    }
  }
  if (l < DF) {
#pragma unroll
    for (int i = 0; i < 6; ++i)
      pout[(size_t)h * (NB * NJ * DF) +
           (size_t)(b * NJ + jq * 6 + i) * DF + l] = acc[i];
  }
}

// ---------------- sum the two half-partials into final output
__global__ __launch_bounds__(512) void k5(const float* __restrict__ po,
                                          float* __restrict__ out) {
  int i = blockIdx.x * 512 + threadIdx.x;       // grid exact: 1572*512 = 804864
  out[i] = po[i] + po[(size_t)(NB * NJ * DF) + i];
}

extern "C" void kernel_launch(void* const* d_in, const int* in_sizes, int n_in,
                              void* d_out, int out_size, void* d_ws, size_t ws_size,
                              hipStream_t stream) {
  const float* sf = (const float*)d_in[0];
  const float* W1 = (const float*)d_in[1];
  const float* b1 = (const float*)d_in[2];
  const float* W2 = (const float*)d_in[3];
  const float* b2 = (const float*)d_in[4];
  float* out = (float*)d_out;
  float* attn = out + (size_t)NB * NJ * DF;     // attention output region
  float* ws = (float*)d_ws;
  float* W1t = ws + WS_W1T;
  float* q_t = ws + WS_QT;
  float* md  = ws + WS_MD;
  float* po  = ws + WS_PO;

  kT <<<235, 256, 0, stream>>>(W1, W1t);
  // h-partials scratch lives in the attention region (overwritten later by k2)
  k1 <<<524, 512, 0, stream>>>(sf, W1t, attn);
  k1b<<<66, 512, 0, stream>>>(attn, W2, b1, b2, q_t);
  k2 <<<512, 512, 0, stream>>>(sf, q_t, attn, md);
  k3 <<<NB * NJ, 256, 0, stream>>>(attn, md);
  k4 <<<512, 768, 0, stream>>>(sf, attn, po);
  k5 <<<1572, 512, 0, stream>>>(po, out);
}

// Round 2
// 835.582 us; speedup vs baseline: 1.2823x; 1.2823x over previous
//
#include <hip/hip_runtime.h>
#include <cstdint>
#include <cstddef>

#define NB 256
#define NS 2500
#define NJ 24
#define DF 131

#define TN 124           // n-rows per LDS tile (124*131*4 = 64976 B < 64 KiB)
#define NHALF 1250       // n-rows handled per block (2 blocks per batch)
#define NTILE 11         // ceil(1250/124)

// ws layout (float offsets)
#define WS_W1T 0u
#define WS_QT  60000u                                  // [NB][DF][NJ]
#define WS_MD  (WS_QT + (unsigned)(NB * DF * NJ))      // [NB][2][48] (m,d per half)
#define WS_PO  (WS_MD + (unsigned)(NB * 2 * 48))       // [2][NB][NJ][DF]

// ---------------- W1 transpose: W1t[c][o] = W1[o][c] ----------------
__global__ __launch_bounds__(256) void kT(const float* __restrict__ W1,
                                          float* __restrict__ W1t) {
  int i = blockIdx.x * 256 + threadIdx.x;
  if (i >= NJ * NS) return;
  int o = i / NS, c = i - o * NS;
  W1t[c * NJ + o] = W1[i];
}

// ---------------- h partials: ph[h][b][o][l] = sum_{c in half} W1t[c][o]*X[b][c][l]
// k4-style: weights are wave-uniform -> s_load broadcast; X via LDS tile.
__global__ __launch_bounds__(768) void kH(const float* __restrict__ sf,
                                          const float* __restrict__ W1t,
                                          float* __restrict__ ph) {
  __shared__ float xs[TN * DF];
  int b = blockIdx.x >> 1;
  int h = blockIdx.x & 1;
  int tid = threadIdx.x;
  int wid = tid >> 6, lane = tid & 63;
  int jq = __builtin_amdgcn_readfirstlane(wid & 3);   // 0..3 -> 6 o's each
  int lg = wid >> 2;                                  // 0..2
  int l = lg * 64 + lane;                             // 0..191, active < DF

  const float* sft = sf + (size_t)b * (NS * DF) + (size_t)h * (NHALF * DF);
  const float* wb = W1t + (size_t)h * (NHALF * NJ) + jq * 6;  // + c*NJ + i

  float acc[6];
#pragma unroll
  for (int i = 0; i < 6; ++i) acc[i] = 0.f;

  const int EC = TN * DF;
  float st[22];
#pragma unroll
  for (int k = 0; k < 22; ++k) {
    int e = tid + k * 768;
    st[k] = (e < EC) ? sft[e] : 0.f;
  }
  int lc = (l < DF) ? l : 0;
  for (int t = 0; t < NTILE; ++t) {
    __syncthreads();
#pragma unroll
    for (int k = 0; k < 22; ++k) {
      int e = tid + k * 768;
      if (e < EC) xs[e] = st[k];
    }
    __syncthreads();
    if (t + 1 < NTILE) {
      size_t base = (size_t)(t + 1) * EC;
#pragma unroll
      for (int k = 0; k < 22; ++k) {
        int e = tid + k * 768;
        bool ok = (e < EC) && ((t + 1) * EC + e < NHALF * DF);
        st[k] = ok ? sft[base + e] : 0.f;
      }
    }
    int nmax = NHALF - t * TN; if (nmax > TN) nmax = TN;
#pragma unroll 4
    for (int n = 0; n < nmax; ++n) {
      float xv = xs[n * DF + lc];               // lanes->l consecutive, bank-clean
#pragma unroll
      for (int i = 0; i < 6; ++i)               // wave-uniform -> s_load
        acc[i] = fmaf(wb[(size_t)(t * TN + n) * NJ + i], xv, acc[i]);
    }
  }
  if (l < DF) {
#pragma unroll
    for (int i = 0; i < 6; ++i)
      ph[(size_t)h * (NB * NJ * DF) +
         (size_t)(b * NJ + jq * 6 + i) * DF + l] = acc[i];
  }
}

// ---------------- reduce 2 partials, relu, query = W2@h + b2, store q^T [b][l][24]
__global__ __launch_bounds__(512) void k1b(const float* __restrict__ ph,
                                           const float* __restrict__ W2,
                                           const float* __restrict__ b1v,
                                           const float* __restrict__ b2v,
                                           float* __restrict__ q_t) {
  int flat = blockIdx.x * 512 + threadIdx.x;
  if (flat >= NB * DF) return;
  int l = flat % DF;
  int b = flat / DF;

  float hv[NJ];
  const float* p0 = ph + (size_t)(b * NJ) * DF + l;
  const float* p1 = p0 + (size_t)NB * NJ * DF;
#pragma unroll
  for (int o = 0; o < NJ; ++o)
    hv[o] = fmaxf(b1v[o] + p0[o * DF] + p1[o * DF], 0.f);

  float q[NJ];
  for (int o = 0; o < NJ; ++o) {
    float s = b2v[o];
#pragma unroll
    for (int i = 0; i < NJ; ++i) s = fmaf(W2[o * NJ + i], hv[i], s);
    q[o] = s;
  }
  float4* qp = (float4*)(q_t + (size_t)flat * NJ);   // 96B-aligned
#pragma unroll
  for (int v = 0; v < 6; ++v)
    qp[v] = make_float4(q[4 * v], q[4 * v + 1], q[4 * v + 2], q[4 * v + 3]);
}

// ---------------- scores + online m/d. block = (batch, n-half). writes raw S.
__global__ __launch_bounds__(512) void k2(const float* __restrict__ sf,
                                          const float* __restrict__ q_t,
                                          float* __restrict__ raw,
                                          float* __restrict__ md) {
  __shared__ float xs[TN * DF];                // flat [n][l], stride 131 (bank-clean)
  __shared__ float lmd[8][6][2];
  int b = blockIdx.x >> 1;
  int h = blockIdx.x & 1;
  int tid = threadIdx.x;
  int wid = tid >> 6, lane = tid & 63;
  int jq = __builtin_amdgcn_readfirstlane(wid >> 1);  // 0..3 -> 6 j's each
  int ng = wid & 1;
  int nl = ng * 64 + lane;                      // 0..127 (valid < TN)

  const float* sft = sf + (size_t)b * (NS * DF) + (size_t)h * (NHALF * DF);
  const float* qb = q_t + (size_t)b * (DF * NJ) + jq * 6;
  float* rawb = raw + (size_t)b * (NJ * NS) + (size_t)h * NHALF;

  float m_loc[6], d_loc[6];
#pragma unroll
  for (int i = 0; i < 6; ++i) { m_loc[i] = -1e30f; d_loc[i] = 0.f; }

  const int EC = TN * DF;                       // 16244
  float st[32];
#pragma unroll
  for (int k = 0; k < 32; ++k) {                // preload tile 0 (flat copy)
    int e = tid + k * 512;
    st[k] = (e < EC) ? sft[e] : 0.f;
  }

  int nle = (nl < TN) ? nl : 0;                 // keep LDS reads in-bounds
  for (int t = 0; t < NTILE; ++t) {
    __syncthreads();
#pragma unroll
    for (int k = 0; k < 32; ++k) {
      int e = tid + k * 512;
      if (e < EC) xs[e] = st[k];
    }
    __syncthreads();
    if (t + 1 < NTILE) {                        // issue next tile's loads now
      size_t base = (size_t)(t + 1) * EC;
#pragma unroll
      for (int k = 0; k < 32; ++k) {
        int e = tid + k * 512;
        bool ok = (e < EC) && ((t + 1) * EC + e < NHALF * DF);
        st[k] = ok ? sft[base + e] : 0.f;
      }
    }
    float s_acc[6];
#pragma unroll
    for (int i = 0; i < 6; ++i) s_acc[i] = 0.f;
    const float* xrow = xs + nle * DF;
    for (int l = 0; l < DF; ++l) {
      float xv = xrow[l];                       // ds_read, (3n+l)%32 conflict-free
#pragma unroll
      for (int i = 0; i < 6; ++i)               // q uniform -> s_load
        s_acc[i] = fmaf(qb[l * NJ + i], xv, s_acc[i]);
    }
    int nrow = t * TN + nl;
    if (nl < TN && nrow < NHALF) {
#pragma unroll
      for (int i = 0; i < 6; ++i) {
        rawb[(size_t)(jq * 6 + i) * NS + nrow] = s_acc[i];
        float mn = fmaxf(m_loc[i], s_acc[i]);
        d_loc[i] = d_loc[i] * __expf(m_loc[i] - mn) + __expf(s_acc[i] - mn);
        m_loc[i] = mn;
      }
    }
  }
  // lane butterfly reduce (m,d) then cross-wave combine
#pragma unroll
  for (int i = 0; i < 6; ++i) {
    float m = m_loc[i], d = d_loc[i];
    for (int off = 32; off > 0; off >>= 1) {
      float mo = __shfl_xor(m, off);
      float dd = __shfl_xor(d, off);
      float nm = fmaxf(m, mo);
      d = d * __expf(m - nm) + dd * __expf(mo - nm);
      m = nm;
    }
    if (lane == 0) { lmd[wid][i][0] = m; lmd[wid][i][1] = d; }
  }
  __syncthreads();
  if (tid < NJ) {
    int j = tid, j6 = j / 6, i = j % 6;
    float m1 = lmd[j6 * 2][i][0],     d1 = lmd[j6 * 2][i][1];
    float m2 = lmd[j6 * 2 + 1][i][0], d2 = lmd[j6 * 2 + 1][i][1];
    float nm = fmaxf(m1, m2);
    float dd = d1 * __expf(m1 - nm) + d2 * __expf(m2 - nm);
    md[(size_t)(b * 2 + h) * 48 + j] = nm;
    md[(size_t)(b * 2 + h) * 48 + 24 + j] = dd;
  }
}

// ---------------- combine half m/d, normalize attention in place
__global__ __launch_bounds__(256) void k3(float* __restrict__ attn,
                                          const float* __restrict__ md) {
  int bj = blockIdx.x;                          // b*24+j
  int b = bj / NJ;
  int j = bj - b * NJ;
  const float* mp = md + (size_t)b * 96;
  float m1 = mp[j], d1 = mp[24 + j], m2 = mp[48 + j], d2 = mp[72 + j];
  float m = fmaxf(m1, m2);
  float r = 1.f / (d1 * __expf(m1 - m) + d2 * __expf(m2 - m));
  float* p = attn + (size_t)bj * NS;
  for (int n = threadIdx.x; n < NS; n += 256)
    p[n] = __expf(p[n] - m) * r;
}

// ---------------- out partials: po[h][b][j][l] = sum_{n in half} A[b][j][n]*X[b][n][l]
__global__ __launch_bounds__(768) void k4(const float* __restrict__ sf,
                                          const float* __restrict__ attn,
                                          float* __restrict__ pout) {
  __shared__ float xs[TN * DF];
  int b = blockIdx.x >> 1;
  int h = blockIdx.x & 1;
  int tid = threadIdx.x;
  int wid = tid >> 6, lane = tid & 63;
  int jq = __builtin_amdgcn_readfirstlane(wid & 3);   // 0..3
  int lg = wid >> 2;                                  // 0..2
  int l = lg * 64 + lane;                             // 0..191, active < DF

  const float* sft = sf + (size_t)b * (NS * DF) + (size_t)h * (NHALF * DF);
  const float* ab = attn + (size_t)(b * NJ + jq * 6) * NS + (size_t)h * NHALF;

  float acc[6];
#pragma unroll
  for (int i = 0; i < 6; ++i) acc[i] = 0.f;

  const int EC = TN * DF;
  float st[22];
#pragma unroll
  for (int k = 0; k < 22; ++k) {
    int e = tid + k * 768;
    st[k] = (e < EC) ? sft[e] : 0.f;
  }
  int lc = (l < DF) ? l : 0;
  for (int t = 0; t < NTILE; ++t) {
    __syncthreads();
#pragma unroll
    for (int k = 0; k < 22; ++k) {
      int e = tid + k * 768;
      if (e < EC) xs[e] = st[k];
    }
    __syncthreads();
    if (t + 1 < NTILE) {
      size_t base = (size_t)(t + 1) * EC;
#pragma unroll
      for (int k = 0; k < 22; ++k) {
        int e = tid + k * 768;
        bool ok = (e < EC) && ((t + 1) * EC + e < NHALF * DF);
        st[k] = ok ? sft[base + e] : 0.f;
      }
    }
    int nmax = NHALF - t * TN; if (nmax > TN) nmax = TN;
#pragma unroll 4
    for (int n = 0; n < nmax; ++n) {
      float xv = xs[n * DF + lc];               // lanes->l consecutive, bank-clean
#pragma unroll
      for (int i = 0; i < 6; ++i)               // attn uniform -> s_load
        acc[i] = fmaf(ab[(size_t)i * NS + t * TN + n], xv, acc[i]);
    }
  }
  if (l < DF) {
#pragma unroll
    for (int i = 0; i < 6; ++i)
      pout[(size_t)h * (NB * NJ * DF) +
           (size_t)(b * NJ + jq * 6 + i) * DF + l] = acc[i];
  }
}

// ---------------- sum the two half-partials into final output
__global__ __launch_bounds__(512) void k5(const float* __restrict__ po,
                                          float* __restrict__ out) {
  int i = blockIdx.x * 512 + threadIdx.x;       // grid exact: 1572*512 = 804864
  out[i] = po[i] + po[(size_t)(NB * NJ * DF) + i];
}

extern "C" void kernel_launch(void* const* d_in, const int* in_sizes, int n_in,
                              void* d_out, int out_size, void* d_ws, size_t ws_size,
                              hipStream_t stream) {
  const float* sf = (const float*)d_in[0];
  const float* W1 = (const float*)d_in[1];
  const float* b1 = (const float*)d_in[2];
  const float* W2 = (const float*)d_in[3];
  const float* b2 = (const float*)d_in[4];
  float* out = (float*)d_out;
  float* attn = out + (size_t)NB * NJ * DF;     // attention output region
  float* ws = (float*)d_ws;
  float* W1t = ws + WS_W1T;
  float* q_t = ws + WS_QT;
  float* md  = ws + WS_MD;
  float* po  = ws + WS_PO;

  kT <<<235, 256, 0, stream>>>(W1, W1t);
  // h-partials live in the po scratch region (reused by k4 afterwards - sequential)
  kH <<<512, 768, 0, stream>>>(sf, W1t, po);
  k1b<<<66, 512, 0, stream>>>(po, W2, b1, b2, q_t);
  k2 <<<512, 512, 0, stream>>>(sf, q_t, attn, md);
  k3 <<<NB * NJ, 256, 0, stream>>>(attn, md);
  k4 <<<512, 768, 0, stream>>>(sf, attn, po);
  k5 <<<1572, 512, 0, stream>>>(po, out);
}

// Round 3
// 823.494 us; speedup vs baseline: 1.3011x; 1.0147x over previous
//
#include <hip/hip_runtime.h>
#include <cstdint>
#include <cstddef>

#define NB 256
#define NS 2500
#define NJ 24
#define DF 131

#define KSEG 8           // reduction-axis segments for kH/k4
#define CSEG 313         // ceil(2500/8); last seg = 309
#define QSEG 4           // n segments for k2
#define SEGN 625         // 2500/4
#define TN 64            // rows per k2 LDS tile
#define LDP 132          // padded row stride (16B-aligned float4 rows)

// ws layout (float offsets)
#define WS_W1T 0u
#define WS_QT  60000u                                  // [NB][DF][NJ]
#define WS_MD  (WS_QT + 804864u)                       // [NB][QSEG][48]
#define WS_PH  (WS_MD + (unsigned)(NB * QSEG * 48))    // [KSEG][NB][NJ][DF] (kH out, reused as k4 po)
#define SEGSTRIDE ((size_t)NB * NJ * DF)               // 804864

// ---------------- W1 transpose: W1t[c][o] = W1[o][c] ----------------
__global__ __launch_bounds__(256) void kT(const float* __restrict__ W1,
                                          float* __restrict__ W1t) {
  int i = blockIdx.x * 256 + threadIdx.x;
  if (i >= NJ * NS) return;
  int o = i / NS, c = i - o * NS;
  W1t[c * NJ + o] = W1[i];
}

// ---------------- h partials, no LDS: ph[s][b][o][l] = sum_{c in seg} W1t[c][o]*X[b][c][l]
__global__ __launch_bounds__(192) void kH(const float* __restrict__ sf,
                                          const float* __restrict__ W1t,
                                          float* __restrict__ ph) {
  int b = blockIdx.x >> 3;
  int s = blockIdx.x & 7;
  int l = threadIdx.x;                          // 0..191, active < DF
  int c0 = s * CSEG;
  int cnt = NS - c0; if (cnt > CSEG) cnt = CSEG;
  const float* xp = sf + (size_t)b * (NS * DF) + (size_t)c0 * DF;
  const float* wp = W1t + (size_t)c0 * NJ;

  float acc[NJ];
#pragma unroll
  for (int o = 0; o < NJ; ++o) acc[o] = 0.f;

  if (l < DF) {
#pragma unroll 2
    for (int c = 0; c < cnt; ++c) {
      float xv = xp[(size_t)c * DF + l];        // coalesced per-lane
#pragma unroll
      for (int o = 0; o < NJ; ++o)              // uniform -> s_load_dwordx8
        acc[o] = fmaf(wp[c * NJ + o], xv, acc[o]);
    }
    float* pp = ph + (size_t)(s * NB + b) * (NJ * DF) + l;
#pragma unroll
    for (int o = 0; o < NJ; ++o) pp[o * DF] = acc[o];
  }
}

// ---------------- reduce KSEG partials, relu, query = W2@h + b2, store q^T [b][l][24]
__global__ __launch_bounds__(512) void k1b(const float* __restrict__ ph,
                                           const float* __restrict__ W2,
                                           const float* __restrict__ b1v,
                                           const float* __restrict__ b2v,
                                           float* __restrict__ q_t) {
  int flat = blockIdx.x * 512 + threadIdx.x;
  if (flat >= NB * DF) return;
  int l = flat % DF;
  int b = flat / DF;

  const float* p0 = ph + (size_t)(b * NJ) * DF + l;
  float hv[NJ];
#pragma unroll
  for (int o = 0; o < NJ; ++o) hv[o] = b1v[o];
  for (int s = 0; s < KSEG; ++s) {
#pragma unroll
    for (int o = 0; o < NJ; ++o) hv[o] += p0[s * SEGSTRIDE + o * DF];
  }
#pragma unroll
  for (int o = 0; o < NJ; ++o) hv[o] = fmaxf(hv[o], 0.f);

  float q[NJ];
  for (int o = 0; o < NJ; ++o) {
    float sv = b2v[o];
#pragma unroll
    for (int i = 0; i < NJ; ++i) sv = fmaf(W2[o * NJ + i], hv[i], sv);
    q[o] = sv;
  }
  float4* qp = (float4*)(q_t + (size_t)flat * NJ);   // 96B-aligned
#pragma unroll
  for (int v = 0; v < 6; ++v)
    qp[v] = make_float4(q[4 * v], q[4 * v + 1], q[4 * v + 2], q[4 * v + 3]);
}

// ---------------- scores + per-seg m/d. block = (batch, n-seg of 625). writes raw S.
__global__ __launch_bounds__(256) void k2(const float* __restrict__ sf,
                                          const float* __restrict__ q_t,
                                          float* __restrict__ raw,
                                          float* __restrict__ md) {
  __shared__ __align__(16) float xs[TN * LDP];  // 64 rows, 132-float padded stride
  int b = blockIdx.x >> 2;
  int s = blockIdx.x & 3;
  int tid = threadIdx.x;
  int wid = tid >> 6, lane = tid & 63;
  int jq = __builtin_amdgcn_readfirstlane(wid); // 0..3 -> 6 j's each

  const float* sft = sf + (size_t)b * (NS * DF) + (size_t)(s * SEGN) * DF;
  const float* qb = q_t + (size_t)b * (DF * NJ) + jq * 6;
  float* rawb = raw + (size_t)b * (NJ * NS) + (size_t)(s * SEGN);

  float m6[6], d6[6];
#pragma unroll
  for (int i = 0; i < 6; ++i) { m6[i] = -1e30f; d6[i] = 0.f; }

  const int NT = (SEGN + TN - 1) / TN;          // 10
  for (int t = 0; t < NT; ++t) {
    int n0 = t * TN;
    int nmax = SEGN - n0; if (nmax > TN) nmax = TN;
    __syncthreads();
    // wave wid copies rows wid*16..wid*16+15, coalesced, padded-dst
#pragma unroll
    for (int rr = 0; rr < 16; ++rr) {
      int r = wid * 16 + rr;
      if (r < nmax) {
        const float* g = sft + (size_t)(n0 + r) * DF;
        float* d = xs + r * LDP;
        d[lane] = g[lane];
        d[64 + lane] = g[64 + lane];
        if (lane < 3) d[128 + lane] = g[128 + lane];
      }
    }
    __syncthreads();
    if (lane < nmax) {
      const float* xrow = xs + lane * LDP;
      float sa[6];
#pragma unroll
      for (int i = 0; i < 6; ++i) sa[i] = 0.f;
      for (int l4 = 0; l4 < 32; ++l4) {
        float4 xv = *(const float4*)(xrow + 4 * l4);   // ds_read_b128, 2-way min
        const float* q4 = qb + (4 * l4) * NJ;
#pragma unroll
        for (int i = 0; i < 6; ++i) sa[i] = fmaf(q4[i], xv.x, sa[i]);
#pragma unroll
        for (int i = 0; i < 6; ++i) sa[i] = fmaf(q4[NJ + i], xv.y, sa[i]);
#pragma unroll
        for (int i = 0; i < 6; ++i) sa[i] = fmaf(q4[2 * NJ + i], xv.z, sa[i]);
#pragma unroll
        for (int i = 0; i < 6; ++i) sa[i] = fmaf(q4[3 * NJ + i], xv.w, sa[i]);
      }
#pragma unroll
      for (int l = 128; l < DF; ++l) {
        float xv = xrow[l];
#pragma unroll
        for (int i = 0; i < 6; ++i) sa[i] = fmaf(qb[l * NJ + i], xv, sa[i]);
      }
      int nr = n0 + lane;
#pragma unroll
      for (int i = 0; i < 6; ++i) {
        rawb[(size_t)(jq * 6 + i) * NS + nr] = sa[i];
        float mn = fmaxf(m6[i], sa[i]);
        d6[i] = d6[i] * __expf(m6[i] - mn) + __expf(sa[i] - mn);
        m6[i] = mn;
      }
    }
  }
  // 64-lane butterfly; idle lanes carry (-inf, 0) = neutral
#pragma unroll
  for (int i = 0; i < 6; ++i) {
    float m = m6[i], d = d6[i];
    for (int off = 32; off > 0; off >>= 1) {
      float mo = __shfl_xor(m, off);
      float dd = __shfl_xor(d, off);
      float nm = fmaxf(m, mo);
      d = d * __expf(m - nm) + dd * __expf(mo - nm);
      m = nm;
    }
    m6[i] = m; d6[i] = d;
  }
  if (lane == 0) {
    float* mp = md + ((size_t)b * QSEG + s) * 48;
#pragma unroll
    for (int i = 0; i < 6; ++i) {
      mp[jq * 6 + i] = m6[i];
      mp[24 + jq * 6 + i] = d6[i];
    }
  }
}

// ---------------- combine seg m/d, normalize attention in place
__global__ __launch_bounds__(256) void k3(float* __restrict__ attn,
                                          const float* __restrict__ md) {
  int bj = blockIdx.x;                          // b*24+j
  int b = bj / NJ;
  int j = bj - b * NJ;
  const float* mp = md + (size_t)b * (QSEG * 48);
  float m = -1e30f, d = 0.f;
#pragma unroll
  for (int s = 0; s < QSEG; ++s) {
    float ms = mp[s * 48 + j], ds = mp[s * 48 + 24 + j];
    float nm = fmaxf(m, ms);
    d = d * __expf(m - nm) + ds * __expf(ms - nm);
    m = nm;
  }
  float r = 1.f / d;
  float* p = attn + (size_t)bj * NS;
  for (int n = threadIdx.x; n < NS; n += 256)
    p[n] = __expf(p[n] - m) * r;
}

// ---------------- out partials, no LDS: po[s][b][o][l] = sum_{n in seg} A[b][o][n]*X[b][n][l]
__global__ __launch_bounds__(192) void k4(const float* __restrict__ sf,
                                          const float* __restrict__ attn,
                                          float* __restrict__ po) {
  int b = blockIdx.x >> 3;
  int s = blockIdx.x & 7;
  int l = threadIdx.x;
  int n0 = s * CSEG;
  int cnt = NS - n0; if (cnt > CSEG) cnt = CSEG;
  const float* xp = sf + (size_t)b * (NS * DF) + (size_t)n0 * DF;
  const float* ap = attn + (size_t)b * (NJ * NS) + n0;

  float acc[NJ];
#pragma unroll
  for (int o = 0; o < NJ; ++o) acc[o] = 0.f;

  if (l < DF) {
#pragma unroll 2
    for (int n = 0; n < cnt; ++n) {
      float xv = xp[(size_t)n * DF + l];        // coalesced per-lane
#pragma unroll
      for (int o = 0; o < NJ; ++o)              // uniform -> s_load
        acc[o] = fmaf(ap[(size_t)o * NS + n], xv, acc[o]);
    }
    float* pp = po + (size_t)(s * NB + b) * (NJ * DF) + l;
#pragma unroll
    for (int o = 0; o < NJ; ++o) pp[o * DF] = acc[o];
  }
}

// ---------------- sum the KSEG half-partials into final output
__global__ __launch_bounds__(512) void k5(const float* __restrict__ po,
                                          float* __restrict__ out) {
  int i = blockIdx.x * 512 + threadIdx.x;       // grid exact: 1572*512 = 804864
  float v = 0.f;
#pragma unroll
  for (int s = 0; s < KSEG; ++s) v += po[s * SEGSTRIDE + i];
  out[i] = v;
}

extern "C" void kernel_launch(void* const* d_in, const int* in_sizes, int n_in,
                              void* d_out, int out_size, void* d_ws, size_t ws_size,
                              hipStream_t stream) {
  const float* sf = (const float*)d_in[0];
  const float* W1 = (const float*)d_in[1];
  const float* b1 = (const float*)d_in[2];
  const float* W2 = (const float*)d_in[3];
  const float* b2 = (const float*)d_in[4];
  float* out = (float*)d_out;
  float* attn = out + (size_t)NB * NJ * DF;     // attention output region
  float* ws = (float*)d_ws;
  float* W1t = ws + WS_W1T;
  float* q_t = ws + WS_QT;
  float* md  = ws + WS_MD;
  float* ph  = ws + WS_PH;                      // also k4's po (sequential lifetimes)

  kT <<<235, 256, 0, stream>>>(W1, W1t);
  kH <<<NB * KSEG, 192, 0, stream>>>(sf, W1t, ph);
  k1b<<<66, 512, 0, stream>>>(ph, W2, b1, b2, q_t);
  k2 <<<NB * QSEG, 256, 0, stream>>>(sf, q_t, attn, md);
  k3 <<<NB * NJ, 256, 0, stream>>>(attn, md);
  k4 <<<NB * KSEG, 192, 0, stream>>>(sf, attn, ph);
  k5 <<<1572, 512, 0, stream>>>(ph, out);
}